// Round 7
// baseline (504.729 us; speedup 1.0000x reference)
//
#include <hip/hip_runtime.h>
#include <hip/hip_bf16.h>

// WindowAttentionRPB v7, MI355X gfx950. Three dispatches:
//  preconv: weights->bf16 (scale folded into Wq), rpb/mask permuted to
//           [kt][ll*4+ni] (kt-major) for the S^T layout.
//  K1 attn: ONE WAVE per (window,head). ZERO LDS, ZERO barriers.
//    - x fragment loaded once: serves as B-frag (Q/K^T GEMM, tok in lanes)
//      and A-frag (V GEMM, tok in lanes) -- identical frag layouts.
//    - S^T = K.Q^T via mfma(bk, aq): kt lands in REGS, q in lanes.
//    - softmax over kt: 16 reg values + shfl_xor(16,32).
//    - PV: O^T = V^T.P^T straight from accumulators -- V's C-layout
//      (kt in regs, sigma(lg,mi,r)) matches P^T's B-frag k-slots exactly;
//      shared permutation cancels in the contraction.
//    - attn-out bf16 -> d_out row q bytes [q*1024, q*1024+512).
//  K2 proj: block = 1 window, 4 waves; reads its own 64 rows, one barrier,
//           overwrites same rows fp32.
// XCD swizzle both: (bid&7) = XCD gets contiguous window range.

#define TOK 64
#define CDIM 256

typedef __attribute__((ext_vector_type(8))) short short8;
typedef __attribute__((ext_vector_type(4))) float f32x4;
typedef __attribute__((ext_vector_type(4))) float float4_t;

__device__ __forceinline__ short f2bf(float f) {
  union { float f; unsigned u; } v; v.f = f;
  unsigned r = v.u + 0x7FFFu + ((v.u >> 16) & 1u);
  return (short)(r >> 16);
}

__device__ __forceinline__ unsigned cvt2(float a, float b) {
  union { __hip_bfloat162 h; unsigned u; } v;
  v.h = __float22bfloat162_rn(make_float2(a, b));
  return v.u;
}

__device__ __forceinline__ short8 pack88(f32x4 lo, f32x4 hi) {
  union { short8 s; unsigned u[4]; } r;
  r.u[0] = cvt2(lo[0], lo[1]);
  r.u[1] = cvt2(lo[2], lo[3]);
  r.u[2] = cvt2(hi[0], hi[1]);
  r.u[3] = cvt2(hi[2], hi[3]);
  return r.s;
}

__global__ void preconv_kernel(const float* __restrict__ qkv_w,
                               const float* __restrict__ proj_w,
                               const float* __restrict__ rpb_table,
                               const int* __restrict__ rpb_index,
                               const float* __restrict__ mask,
                               short* __restrict__ wqkv,
                               short* __restrict__ wproj,
                               float* __restrict__ rpbP,
                               float* __restrict__ maskP) {
  int idx = blockIdx.x * blockDim.x + threadIdx.x;
  const float scale = 0.17677669529663687f; // 1/sqrt(32), folded into Wq
  const int NW1 = 768 * 256;
  const int NW2 = NW1 + 256 * 256;
  const int NW3 = NW2 + 8 * 64 * 64;
  const int NW4 = NW3 + 64 * 64 * 64;
  if (idx < NW1) {
    float v = qkv_w[idx];
    if (idx < 256 * 256) v *= scale;
    wqkv[idx] = f2bf(v);
  } else if (idx < NW2) {
    int i = idx - NW1;
    wproj[i] = f2bf(proj_w[i]);
  } else if (idx < NW3) {
    int i = idx - NW2;             // [h][kt][ll*4+ni], q = ni*16+ll
    int h = i >> 12;
    int pos = i & 4095;
    int kt = pos >> 6;
    int t = pos & 63;
    int llv = t >> 2, ni = t & 3;
    int q = ni * 16 + llv;
    rpbP[i] = rpb_table[rpb_index[q * 64 + kt] * 8 + h];
  } else if (idx < NW4) {
    int i = idx - NW3;             // [win][kt][ll*4+ni]
    int win = i >> 12;
    int pos = i & 4095;
    int kt = pos >> 6;
    int t = pos & 63;
    int llv = t >> 2, ni = t & 3;
    int q = ni * 16 + llv;
    maskP[i] = mask[win * 4096 + q * 64 + kt];
  }
}

// ---------------- K1: one wave per (window, head), no LDS ----------------
__global__ void __launch_bounds__(64, 3) attn_kernel(
    const float* __restrict__ x, const float* __restrict__ qkv_b,
    const short* __restrict__ wqkv,
    const float* __restrict__ rpbP, const float* __restrict__ maskP,
    float* __restrict__ out) {
  const int bid = blockIdx.x;
  const int sid = (bid & 7) * 2048 + (bid >> 3);  // XCD-contiguous windows
  const int w = sid >> 3;              // window 0..2047
  const int h = sid & 7;               // head
  const int lane = threadIdx.x & 63;
  const int lg = lane >> 4;
  const int ll = lane & 15;
  const float scale = 0.17677669529663687f;

  const float* xb = x + (size_t)w * TOK * CDIM;

  // ---- single QKV loop. xf: tok in lanes, x-chan in regs.
  // aqk[ni][j]: Q/K transposed C[c][tok] (c in regs, tok in lanes)
  // av[mi][hf]: V normal C[kt_tok][d]   (kt in regs, d in lanes)
  f32x4 aqk[4][4] = {};
  f32x4 av[4][2] = {};
#pragma unroll
  for (int ks = 0; ks < 8; ++ks) {
    const int k0 = ks * 32 + lg * 8;
    short8 xf[4];
#pragma unroll
    for (int ni = 0; ni < 4; ++ni) {
      const float* px = xb + (ni * 16 + ll) * 256 + k0;
      xf[ni] = pack88(*reinterpret_cast<const float4_t*>(px),
                      *reinterpret_cast<const float4_t*>(px + 4));
    }
#pragma unroll
    for (int j = 0; j < 4; ++j) {
      const int cbase = (j >> 1) * 256 + h * 32 + (j & 1) * 16;
      short8 wf = *reinterpret_cast<const short8*>(wqkv + (cbase + ll) * 256 + k0);
#pragma unroll
      for (int ni = 0; ni < 4; ++ni)
        aqk[ni][j] = __builtin_amdgcn_mfma_f32_16x16x32_bf16(wf, xf[ni], aqk[ni][j], 0, 0, 0);
    }
#pragma unroll
    for (int hf = 0; hf < 2; ++hf) {
      short8 wv = *reinterpret_cast<const short8*>(
          wqkv + (512 + h * 32 + hf * 16 + ll) * 256 + k0);
#pragma unroll
      for (int mi = 0; mi < 4; ++mi)
        av[mi][hf] = __builtin_amdgcn_mfma_f32_16x16x32_bf16(xf[mi], wv, av[mi][hf], 0, 0, 0);
    }
  }

  // ---- Q/K frags from accumulators (shared d-permutation cancels in S)
  f32x4 bj[4];
#pragma unroll
  for (int j = 0; j < 4; ++j) {
    float4_t t = *reinterpret_cast<const float4_t*>(
        qkv_b + (j >> 1) * 256 + h * 32 + (j & 1) * 16 + lg * 4);
    bj[j] = (j < 2) ? t * scale : t;
  }
  short8 aq[4], bk[4];
#pragma unroll
  for (int ni = 0; ni < 4; ++ni) {
    aq[ni] = pack88(aqk[ni][0] + bj[0], aqk[ni][1] + bj[1]);
    bk[ni] = pack88(aqk[ni][2] + bj[2], aqk[ni][3] + bj[3]);
  }

  // ---- V frags from accumulators: kt in regs, sigma(lg,mi,r) slot map
  short8 vf[2][2];  // [hf][ks: kt 0..31 / 32..63]
#pragma unroll
  for (int hf = 0; hf < 2; ++hf) {
    float bb = qkv_b[512 + h * 32 + hf * 16 + ll];
    f32x4 b4{bb, bb, bb, bb};
    vf[hf][0] = pack88(av[0][hf] + b4, av[1][hf] + b4);
    vf[hf][1] = pack88(av[2][hf] + b4, av[3][hf] + b4);
  }

  // ---- S^T = K.Q^T + rpb^T + mask^T  (rows kt = 16mi+lg*4+r, cols q = 16ni+ll)
  f32x4 sa[4][4];
  {
    f32x4 z{0.0f, 0.0f, 0.0f, 0.0f};
#pragma unroll
    for (int mi = 0; mi < 4; ++mi)
#pragma unroll
      for (int ni = 0; ni < 4; ++ni)
        sa[mi][ni] = __builtin_amdgcn_mfma_f32_16x16x32_bf16(bk[mi], aq[ni], z, 0, 0, 0);
    const float4_t* rp4 = reinterpret_cast<const float4_t*>(rpbP) + h * 1024;
    const float4_t* mk4 = reinterpret_cast<const float4_t*>(maskP) + (w & 63) * 1024;
#pragma unroll
    for (int mi = 0; mi < 4; ++mi)
#pragma unroll
      for (int r = 0; r < 4; ++r) {
        int kt = mi * 16 + lg * 4 + r;
        float4_t f = rp4[kt * 16 + ll];
        float4_t g = mk4[kt * 16 + ll];
#pragma unroll
        for (int ni = 0; ni < 4; ++ni)
          sa[mi][ni][r] += f[ni] + g[ni];
      }
  }

  // ---- softmax over kt, per ni (q = 16ni+ll): 16 reg values + shfl 16/32
  float rinv[4];
#pragma unroll
  for (int ni = 0; ni < 4; ++ni) {
    float m = sa[0][ni][0];
#pragma unroll
    for (int mi = 0; mi < 4; ++mi)
#pragma unroll
      for (int r = 0; r < 4; ++r) m = fmaxf(m, sa[mi][ni][r]);
    m = fmaxf(m, __shfl_xor(m, 16));
    m = fmaxf(m, __shfl_xor(m, 32));
    float s = 0.f;
#pragma unroll
    for (int mi = 0; mi < 4; ++mi)
#pragma unroll
      for (int r = 0; r < 4; ++r) {
        float e = __expf(sa[mi][ni][r] - m);
        sa[mi][ni][r] = e;
        s += e;
      }
    s += __shfl_xor(s, 16);
    s += __shfl_xor(s, 32);
    rinv[ni] = 1.0f / s;
  }

  // ---- PV straight from registers: O^T[d][q] = sum_kt V^T[d][kt] P^T[kt][q]
  f32x4 oa[2][4] = {};
#pragma unroll
  for (int ni = 0; ni < 4; ++ni) {
    short8 pf0 = pack88(sa[0][ni], sa[1][ni]);   // kt 0..31, sigma-matched
    short8 pf1 = pack88(sa[2][ni], sa[3][ni]);   // kt 32..63
#pragma unroll
    for (int hf = 0; hf < 2; ++hf) {
      oa[hf][ni] = __builtin_amdgcn_mfma_f32_16x16x32_bf16(vf[hf][0], pf0, oa[hf][ni], 0, 0, 0);
      oa[hf][ni] = __builtin_amdgcn_mfma_f32_16x16x32_bf16(vf[hf][1], pf1, oa[hf][ni], 0, 0, 0);
    }
  }

  // ---- normalize by rinv (q = col = lane), store attn-out bf16 into d_out
  char* ob = reinterpret_cast<char*>(out) + (size_t)w * TOK * 1024;
#pragma unroll
  for (int hf = 0; hf < 2; ++hf)
#pragma unroll
    for (int ni = 0; ni < 4; ++ni) {
      f32x4 v = oa[hf][ni] * rinv[ni];
      int q = ni * 16 + ll;
      union { unsigned long long q64; unsigned u[2]; } pk;
      pk.u[0] = cvt2(v[0], v[1]);
      pk.u[1] = cvt2(v[2], v[3]);
      *reinterpret_cast<unsigned long long*>(
          ob + (size_t)q * 1024 + h * 64 + hf * 32 + lg * 8) = pk.q64;
    }
}

// ---------------- K2: proj over one window (64 toks) ----------------
__global__ void __launch_bounds__(256, 3) proj_kernel(
    const short* __restrict__ wproj, const float* __restrict__ proj_b,
    float* __restrict__ out) {
  const int bid = blockIdx.x;
  const int t = (bid & 7) * 256 + (bid >> 3);   // window, XCD-matched to K1
  const int wv = threadIdx.x >> 6;              // oc quarter (64 oc)
  const int lane = threadIdx.x & 63;
  const int lg = lane >> 4;
  const int ll = lane & 15;
  const char* ab = reinterpret_cast<const char*>(out) + (size_t)t * TOK * 1024;

  // C[oc][tok] = Wp[oc][:] . attnout[tok][:]
  f32x4 pa[4][4] = {};   // [jj: oc 16-tile][ni: tok 16-tile]
#pragma unroll
  for (int ks = 0; ks < 8; ++ks) {
    const int k0 = ks * 32 + lg * 8;
    short8 af[4];
#pragma unroll
    for (int ni = 0; ni < 4; ++ni)
      af[ni] = *reinterpret_cast<const short8*>(
          ab + (size_t)(ni * 16 + ll) * 1024 + k0 * 2);
#pragma unroll
    for (int jj = 0; jj < 4; ++jj) {
      short8 wf = *reinterpret_cast<const short8*>(
          wproj + (wv * 64 + jj * 16 + ll) * 256 + k0);
#pragma unroll
      for (int ni = 0; ni < 4; ++ni)
        pa[jj][ni] = __builtin_amdgcn_mfma_f32_16x16x32_bf16(wf, af[ni], pa[jj][ni], 0, 0, 0);
    }
  }
  __syncthreads();  // all waves' attn-out reads done before overwriting rows

  float* op = out + (size_t)t * TOK * CDIM;
#pragma unroll
  for (int jj = 0; jj < 4; ++jj) {
    int oc0 = wv * 64 + jj * 16 + lg * 4;
    float4_t pb = *reinterpret_cast<const float4_t*>(proj_b + oc0);
#pragma unroll
    for (int ni = 0; ni < 4; ++ni) {
      f32x4 v = pa[jj][ni] + pb;
      *reinterpret_cast<float4_t*>(op + (ni * 16 + ll) * 256 + oc0) = v;
    }
  }
}

extern "C" void kernel_launch(void* const* d_in, const int* in_sizes, int n_in,
                              void* d_out, int out_size, void* d_ws, size_t ws_size,
                              hipStream_t stream) {
  const float* x        = (const float*)d_in[0];
  const float* mask     = (const float*)d_in[1];
  const float* qkv_w    = (const float*)d_in[2];
  const float* qkv_b    = (const float*)d_in[3];
  const float* proj_w   = (const float*)d_in[4];
  const float* proj_b   = (const float*)d_in[5];
  const float* rpb_tab  = (const float*)d_in[6];
  const int*   rpb_idx  = (const int*)d_in[7];
  float* out = (float*)d_out;

  short* wqkv  = (short*)d_ws;                  // 196608 shorts
  short* wproj = wqkv + 768 * 256;              // 65536 shorts
  float* rpbP  = (float*)(wproj + 256 * 256);   // 32768 floats
  float* maskP = rpbP + 8 * 64 * 64;            // 262144 floats

  int total = 768 * 256 + 256 * 256 + 8 * 64 * 64 + 64 * 64 * 64;
  preconv_kernel<<<(total + 255) / 256, 256, 0, stream>>>(
      qkv_w, proj_w, rpb_tab, rpb_idx, mask, wqkv, wproj, rpbP, maskP);

  int B = in_sizes[0] / (TOK * CDIM);  // 2048
  attn_kernel<<<B * 8, 64, 0, stream>>>(x, qkv_b, wqkv, rpbP, maskP, out);
  proj_kernel<<<B, 256, 0, stream>>>(wproj, proj_b, out);
}

// Round 8
// 296.572 us; speedup vs baseline: 1.7019x; 1.7019x over previous
//
#include <hip/hip_runtime.h>
#include <hip/hip_bf16.h>

// WindowAttentionRPB v8, MI355X gfx950. Four dispatches:
//  preconv: weights->bf16 (scale folded into Wq), rpb/mask permuted [kt][q].
//  xconv:   x fp32 -> bf16, stored in UPPER 512B of each 1024B d_out row.
//  K1 attn: ONE WAVE per (window,head). Zero LDS/barriers. All-register:
//    x bf16 frag loaded once (upper halves of d_out rows); Q/K^T GEMM and
//    V GEMM share it. S^T = K.Q^T (kt in regs, q in lanes); PV straight
//    from accumulators (shared sigma permutation cancels). attn-out bf16
//    -> LOWER 512B of d_out rows. __launch_bounds__(64,2): 256-reg budget
//    (v7's (64,3)=170 cap caused ~500MB spill traffic).
//  K2 proj: block = 1 window; reads lower halves, one barrier, overwrites
//    full rows fp32.
// XCD swizzle: (bid&7)=XCD owns contiguous window range; a window's 8 heads
// are consecutive blocks on one XCD (L2-hot x reuse).

#define TOK 64
#define CDIM 256

typedef __attribute__((ext_vector_type(8))) short short8;
typedef __attribute__((ext_vector_type(4))) float f32x4;
typedef __attribute__((ext_vector_type(4))) float float4_t;

__device__ __forceinline__ short f2bf(float f) {
  union { float f; unsigned u; } v; v.f = f;
  unsigned r = v.u + 0x7FFFu + ((v.u >> 16) & 1u);
  return (short)(r >> 16);
}

__device__ __forceinline__ unsigned cvt2(float a, float b) {
  union { __hip_bfloat162 h; unsigned u; } v;
  v.h = __float22bfloat162_rn(make_float2(a, b));
  return v.u;
}

__device__ __forceinline__ short8 pack88(f32x4 lo, f32x4 hi) {
  union { short8 s; unsigned u[4]; } r;
  r.u[0] = cvt2(lo[0], lo[1]);
  r.u[1] = cvt2(lo[2], lo[3]);
  r.u[2] = cvt2(hi[0], hi[1]);
  r.u[3] = cvt2(hi[2], hi[3]);
  return r.s;
}

__global__ void preconv_kernel(const float* __restrict__ qkv_w,
                               const float* __restrict__ proj_w,
                               const float* __restrict__ rpb_table,
                               const int* __restrict__ rpb_index,
                               const float* __restrict__ mask,
                               short* __restrict__ wqkv,
                               short* __restrict__ wproj,
                               float* __restrict__ rpbP,
                               float* __restrict__ maskP) {
  int idx = blockIdx.x * blockDim.x + threadIdx.x;
  const float scale = 0.17677669529663687f; // 1/sqrt(32), folded into Wq
  const int NW1 = 768 * 256;
  const int NW2 = NW1 + 256 * 256;
  const int NW3 = NW2 + 8 * 64 * 64;
  const int NW4 = NW3 + 64 * 64 * 64;
  if (idx < NW1) {
    float v = qkv_w[idx];
    if (idx < 256 * 256) v *= scale;
    wqkv[idx] = f2bf(v);
  } else if (idx < NW2) {
    int i = idx - NW1;
    wproj[i] = f2bf(proj_w[i]);
  } else if (idx < NW3) {
    int i = idx - NW2;             // [h][kt][ll*4+ni], q = ni*16+ll
    int h = i >> 12;
    int pos = i & 4095;
    int kt = pos >> 6;
    int t = pos & 63;
    int llv = t >> 2, ni = t & 3;
    int q = ni * 16 + llv;
    rpbP[i] = rpb_table[rpb_index[q * 64 + kt] * 8 + h];
  } else if (idx < NW4) {
    int i = idx - NW3;             // [win][kt][ll*4+ni]
    int win = i >> 12;
    int pos = i & 4095;
    int kt = pos >> 6;
    int t = pos & 63;
    int llv = t >> 2, ni = t & 3;
    int q = ni * 16 + llv;
    maskP[i] = mask[win * 4096 + q * 64 + kt];
  }
}

// ---------------- xconv: x fp32 -> bf16 into d_out upper halves ----------
__global__ void __launch_bounds__(256) xconv_kernel(
    const float* __restrict__ x, float* out) {
  int idx = blockIdx.x * blockDim.x + threadIdx.x;   // [0, 131072*8)
  int row = idx >> 3;
  int seg = idx & 7;
  const float4_t* s4 = reinterpret_cast<const float4_t*>(
      x + (size_t)row * 256 + seg * 32);
  char* dst = reinterpret_cast<char*>(out) + (size_t)row * 1024 + 512 + seg * 64;
#pragma unroll
  for (int j = 0; j < 4; ++j)
    *reinterpret_cast<short8*>(dst + j * 16) = pack88(s4[2 * j], s4[2 * j + 1]);
}

// ---------------- K1: one wave per (window, head), no LDS ----------------
__global__ void __launch_bounds__(64, 2) attn_kernel(
    const float* __restrict__ qkv_b, const short* __restrict__ wqkv,
    const float* __restrict__ rpbP, const float* __restrict__ maskP,
    float* out) {
  const int bid = blockIdx.x;
  const int sid = (bid & 7) * 2048 + (bid >> 3);  // XCD-contiguous
  const int w = sid >> 3;              // window 0..2047
  const int h = sid & 7;               // head
  const int lane = threadIdx.x & 63;
  const int lg = lane >> 4;
  const int ll = lane & 15;
  const float scale = 0.17677669529663687f;

  // bf16 x: upper 512B of each row
  const char* xb = reinterpret_cast<const char*>(out) + (size_t)w * TOK * 1024 + 512;

  // ---- single QKV loop. xf: tok in lanes, x-chan in regs.
  f32x4 aqk[4][4] = {};   // Q/K transposed C[c][tok]
  f32x4 av[4][2] = {};    // V normal C[kt][d]
#pragma unroll 2
  for (int ks = 0; ks < 8; ++ks) {
    const int k0 = ks * 32 + lg * 8;
    short8 xf[4];
#pragma unroll
    for (int ni = 0; ni < 4; ++ni)
      xf[ni] = *reinterpret_cast<const short8*>(
          xb + (size_t)(ni * 16 + ll) * 1024 + k0 * 2);
#pragma unroll
    for (int j = 0; j < 4; ++j) {
      const int cbase = (j >> 1) * 256 + h * 32 + (j & 1) * 16;
      short8 wf = *reinterpret_cast<const short8*>(wqkv + (cbase + ll) * 256 + k0);
#pragma unroll
      for (int ni = 0; ni < 4; ++ni)
        aqk[ni][j] = __builtin_amdgcn_mfma_f32_16x16x32_bf16(wf, xf[ni], aqk[ni][j], 0, 0, 0);
    }
#pragma unroll
    for (int hf = 0; hf < 2; ++hf) {
      short8 wv = *reinterpret_cast<const short8*>(
          wqkv + (512 + h * 32 + hf * 16 + ll) * 256 + k0);
#pragma unroll
      for (int mi = 0; mi < 4; ++mi)
        av[mi][hf] = __builtin_amdgcn_mfma_f32_16x16x32_bf16(xf[mi], wv, av[mi][hf], 0, 0, 0);
    }
  }

  // ---- Q/K frags from accumulators (shared d-permutation cancels in S)
  f32x4 bj[4];
#pragma unroll
  for (int j = 0; j < 4; ++j) {
    float4_t t = *reinterpret_cast<const float4_t*>(
        qkv_b + (j >> 1) * 256 + h * 32 + (j & 1) * 16 + lg * 4);
    bj[j] = (j < 2) ? t * scale : t;
  }
  short8 aq[4], bk[4];
#pragma unroll
  for (int ni = 0; ni < 4; ++ni) {
    aq[ni] = pack88(aqk[ni][0] + bj[0], aqk[ni][1] + bj[1]);
    bk[ni] = pack88(aqk[ni][2] + bj[2], aqk[ni][3] + bj[3]);
  }

  // ---- V frags: kt in regs, sigma(lg,mi,r) slot map
  short8 vf[2][2];  // [hf][kt-half]
#pragma unroll
  for (int hf = 0; hf < 2; ++hf) {
    float bb = qkv_b[512 + h * 32 + hf * 16 + ll];
    f32x4 b4{bb, bb, bb, bb};
    vf[hf][0] = pack88(av[0][hf] + b4, av[1][hf] + b4);
    vf[hf][1] = pack88(av[2][hf] + b4, av[3][hf] + b4);
  }

  // ---- S^T = K.Q^T + rpb^T + mask^T (rows kt = 16mi+lg*4+r, cols q = 16ni+ll)
  f32x4 sa[4][4];
  {
    f32x4 z{0.0f, 0.0f, 0.0f, 0.0f};
#pragma unroll
    for (int mi = 0; mi < 4; ++mi)
#pragma unroll
      for (int ni = 0; ni < 4; ++ni)
        sa[mi][ni] = __builtin_amdgcn_mfma_f32_16x16x32_bf16(bk[mi], aq[ni], z, 0, 0, 0);
    const float4_t* rp4 = reinterpret_cast<const float4_t*>(rpbP) + h * 1024;
    const float4_t* mk4 = reinterpret_cast<const float4_t*>(maskP) + (w & 63) * 1024;
#pragma unroll
    for (int mi = 0; mi < 4; ++mi)
#pragma unroll
      for (int r = 0; r < 4; ++r) {
        int kt = mi * 16 + lg * 4 + r;
        float4_t f = rp4[kt * 16 + ll];
        float4_t g = mk4[kt * 16 + ll];
#pragma unroll
        for (int ni = 0; ni < 4; ++ni)
          sa[mi][ni][r] += f[ni] + g[ni];
      }
  }

  // ---- softmax over kt per q-col: 16 reg values + shfl_xor(16,32)
  float rinv[4];
#pragma unroll
  for (int ni = 0; ni < 4; ++ni) {
    float m = sa[0][ni][0];
#pragma unroll
    for (int mi = 0; mi < 4; ++mi)
#pragma unroll
      for (int r = 0; r < 4; ++r) m = fmaxf(m, sa[mi][ni][r]);
    m = fmaxf(m, __shfl_xor(m, 16));
    m = fmaxf(m, __shfl_xor(m, 32));
    float s = 0.f;
#pragma unroll
    for (int mi = 0; mi < 4; ++mi)
#pragma unroll
      for (int r = 0; r < 4; ++r) {
        float e = __expf(sa[mi][ni][r] - m);
        sa[mi][ni][r] = e;
        s += e;
      }
    s += __shfl_xor(s, 16);
    s += __shfl_xor(s, 32);
    rinv[ni] = 1.0f / s;
  }

  // ---- PV straight from registers: O^T[d][q] = sum_kt V^T[d][kt] P^T[kt][q]
  f32x4 oa[2][4] = {};
#pragma unroll
  for (int ni = 0; ni < 4; ++ni) {
    short8 pf0 = pack88(sa[0][ni], sa[1][ni]);   // kt 0..31
    short8 pf1 = pack88(sa[2][ni], sa[3][ni]);   // kt 32..63
#pragma unroll
    for (int hf = 0; hf < 2; ++hf) {
      oa[hf][ni] = __builtin_amdgcn_mfma_f32_16x16x32_bf16(vf[hf][0], pf0, oa[hf][ni], 0, 0, 0);
      oa[hf][ni] = __builtin_amdgcn_mfma_f32_16x16x32_bf16(vf[hf][1], pf1, oa[hf][ni], 0, 0, 0);
    }
  }

  // ---- normalize, store attn-out bf16 into lower halves of d_out rows
  char* ob = reinterpret_cast<char*>(out) + (size_t)w * TOK * 1024;
#pragma unroll
  for (int hf = 0; hf < 2; ++hf)
#pragma unroll
    for (int ni = 0; ni < 4; ++ni) {
      f32x4 v = oa[hf][ni] * rinv[ni];
      int q = ni * 16 + ll;
      union { unsigned long long q64; unsigned u[2]; } pk;
      pk.u[0] = cvt2(v[0], v[1]);
      pk.u[1] = cvt2(v[2], v[3]);
      *reinterpret_cast<unsigned long long*>(
          ob + (size_t)q * 1024 + h * 64 + hf * 32 + lg * 8) = pk.q64;
    }
}

// ---------------- K2: proj over one window (64 toks) ----------------
__global__ void __launch_bounds__(256, 3) proj_kernel(
    const short* __restrict__ wproj, const float* __restrict__ proj_b,
    float* out) {
  const int bid = blockIdx.x;
  const int t = (bid & 7) * 256 + (bid >> 3);   // window, XCD-matched to K1
  const int wv = threadIdx.x >> 6;              // oc quarter (64 oc)
  const int lane = threadIdx.x & 63;
  const int lg = lane >> 4;
  const int ll = lane & 15;
  const char* ab = reinterpret_cast<const char*>(out) + (size_t)t * TOK * 1024;

  // C[oc][tok] = Wp[oc][:] . attnout[tok][:]
  f32x4 pa[4][4] = {};   // [jj: oc 16-tile][ni: tok 16-tile]
#pragma unroll
  for (int ks = 0; ks < 8; ++ks) {
    const int k0 = ks * 32 + lg * 8;
    short8 af[4];
#pragma unroll
    for (int ni = 0; ni < 4; ++ni)
      af[ni] = *reinterpret_cast<const short8*>(
          ab + (size_t)(ni * 16 + ll) * 1024 + k0 * 2);
#pragma unroll
    for (int jj = 0; jj < 4; ++jj) {
      short8 wf = *reinterpret_cast<const short8*>(
          wproj + (wv * 64 + jj * 16 + ll) * 256 + k0);
#pragma unroll
      for (int ni = 0; ni < 4; ++ni)
        pa[jj][ni] = __builtin_amdgcn_mfma_f32_16x16x32_bf16(wf, af[ni], pa[jj][ni], 0, 0, 0);
    }
  }
  __syncthreads();  // all waves' attn-out reads done before overwriting rows

  float* op = out + (size_t)t * TOK * CDIM;
#pragma unroll
  for (int jj = 0; jj < 4; ++jj) {
    int oc0 = wv * 64 + jj * 16 + lg * 4;
    float4_t pb = *reinterpret_cast<const float4_t*>(proj_b + oc0);
#pragma unroll
    for (int ni = 0; ni < 4; ++ni) {
      f32x4 v = pa[jj][ni] + pb;
      *reinterpret_cast<float4_t*>(op + (ni * 16 + ll) * 256 + oc0) = v;
    }
  }
}

extern "C" void kernel_launch(void* const* d_in, const int* in_sizes, int n_in,
                              void* d_out, int out_size, void* d_ws, size_t ws_size,
                              hipStream_t stream) {
  const float* x        = (const float*)d_in[0];
  const float* mask     = (const float*)d_in[1];
  const float* qkv_w    = (const float*)d_in[2];
  const float* qkv_b    = (const float*)d_in[3];
  const float* proj_w   = (const float*)d_in[4];
  const float* proj_b   = (const float*)d_in[5];
  const float* rpb_tab  = (const float*)d_in[6];
  const int*   rpb_idx  = (const int*)d_in[7];
  float* out = (float*)d_out;

  short* wqkv  = (short*)d_ws;                  // 196608 shorts
  short* wproj = wqkv + 768 * 256;              // 65536 shorts
  float* rpbP  = (float*)(wproj + 256 * 256);   // 32768 floats
  float* maskP = rpbP + 8 * 64 * 64;            // 262144 floats

  int total = 768 * 256 + 256 * 256 + 8 * 64 * 64 + 64 * 64 * 64;
  preconv_kernel<<<(total + 255) / 256, 256, 0, stream>>>(
      qkv_w, proj_w, rpb_tab, rpb_idx, mask, wqkv, wproj, rpbP, maskP);

  int B = in_sizes[0] / (TOK * CDIM);  // 2048
  xconv_kernel<<<B * TOK * 8 / 256, 256, 0, stream>>>(x, out);
  attn_kernel<<<B * 8, 64, 0, stream>>>(qkv_b, wqkv, rpbP, maskP, out);
  proj_kernel<<<B, 256, 0, stream>>>(wproj, proj_b, out);
}